// Round 3
// baseline (559.653 us; speedup 1.0000x reference)
//
#include <hip/hip_runtime.h>
#include <math.h>

#define NB 16384   // batch
#define ND 128     // d_model
#define NS 5       // negatives

// One row per 32-lane half-wave (2 rows per wave): 8192 waves = 32 waves/CU
// resident in a single occupancy pass; each half issues its 6 embedding-row
// gathers (dwordx4, 512B/half coalesced) before any reduction so 6 loads per
// half are in flight. Butterflies for all 6 samples are interleaved so their
// lgkm chains overlap. __launch_bounds__(256,8) pins VGPR<=64 for 8 blocks/CU.
__global__ __launch_bounds__(256, 8) void ws_negsamp_kernel(
    const float* __restrict__ h,
    const float* __restrict__ emb,
    const int*   __restrict__ tgt,
    const int*   __restrict__ neg,
    float*       __restrict__ out)
{
    const int wave = (blockIdx.x * blockDim.x + threadIdx.x) >> 6;
    const int lane = threadIdx.x & 63;
    const int half = lane >> 5;   // which row of the pair
    const int hl   = lane & 31;   // lane within half
    const int row  = wave * 2 + half;

    // h row: 32 lanes x float4 = full 512B row
    const float4 hv = *reinterpret_cast<const float4*>(h + (size_t)row * ND + hl * 4);

    int idx[6];
    idx[0] = tgt[row];
#pragma unroll
    for (int s = 0; s < NS; ++s) idx[s + 1] = neg[row * NS + s];

    // issue all 6 gathers before any use
    float4 ev[6];
#pragma unroll
    for (int j = 0; j < 6; ++j)
        ev[j] = *reinterpret_cast<const float4*>(emb + (size_t)idx[j] * ND + hl * 4);

    float sum[6];
#pragma unroll
    for (int j = 0; j < 6; ++j)
        sum[j] = hv.x * ev[j].x + hv.y * ev[j].y + hv.z * ev[j].z + hv.w * ev[j].w;

    // 6 independent 5-step butterflies, interleaved so chains overlap
#pragma unroll
    for (int off = 16; off >= 1; off >>= 1) {
#pragma unroll
        for (int j = 0; j < 6; ++j)
            sum[j] += __shfl_xor(sum[j], off, 64);
    }

    // output layout (flat, return order): pos_out[NB], pos_label[NB],
    // neg_out[NB*NS], neg_label[NB*NS]
    if (hl == 0) {
        out[row]      = 1.0f / (1.0f + __expf(-sum[0]));  // pos_out
        out[NB + row] = 1.0f;                             // pos_label
#pragma unroll
        for (int s = 0; s < NS; ++s) {
            out[2 * NB + row * NS + s]           = 1.0f / (1.0f + __expf(-sum[s + 1]));
            out[2 * NB + NB * NS + row * NS + s] = 0.0f;
        }
    }
}

extern "C" void kernel_launch(void* const* d_in, const int* in_sizes, int n_in,
                              void* d_out, int out_size, void* d_ws, size_t ws_size,
                              hipStream_t stream) {
    const float* h   = (const float*)d_in[0];
    const float* emb = (const float*)d_in[1];
    const int*   tgt = (const int*)d_in[2];
    const int*   neg = (const int*)d_in[3];
    float*       out = (float*)d_out;

    // 2 rows per wave, 4 waves per 256-thread block
    const int blocks = NB / 8;  // 2048
    ws_negsamp_kernel<<<blocks, 256, 0, stream>>>(h, emb, tgt, neg, out);
}